// Round 15
// baseline (297.544 us; speedup 1.0000x reference)
//
#include <hip/hip_runtime.h>
#include <hip/hip_bf16.h>
#include <math.h>

// GCN 2-layer: out = log_softmax( GCN2( relu( GCN1(x) ) ) )
// GCNConv: out = D^-1/2 A D^-1/2 (X W) + (X W)/deg + b,  deg = 1 + indeg(dst)
//
// Round 15: r14 structure (best, 288us) + hw2 rows shrunk 64->48 bf16 (96B).
// agg2's FETCH floor = 8 XCDs x hw2 buffer size (each non-coherent L2 fills
// ~every row it touches; r14 measured 91MB ~= the 12.8MB x 7.1 model). 48-wide
// rows cut the floor 25%. Lanes b>=6 clamp loads to offset 0; their vals are
// already masked to -inf by the f<47 guard. gemm2 stores cols<48 at stride 48.

#define CAP 64
#define NBSHIFT 10
#define BCAP 20480
typedef unsigned short u16;

__device__ __forceinline__ u16 f2bf(float f) {
    __hip_bfloat16 h = __float2bfloat16(f);
    return *reinterpret_cast<u16*>(&h);
}

// ---------------- fused: gemm1 (blocks [0,GB)) || bin_edges (blocks [GB,GB+512)) ----------------
// gemm1: K=128 in 4 chunks of 32. LDS/chunk: xs 64x36 fp32 + Wp 32x64 fp32 = 17408 B.

#define KC 32
#define KCP 36
#define GEMM_SMEM (64 * KCP * 4 + KC * 64 * 4)   // 17408 B

__global__ __launch_bounds__(256) void gemm1_bin(const float* __restrict__ X,
                                                 const float* __restrict__ W,
                                                 u16* __restrict__ OUT,
                                                 const int* __restrict__ src,
                                                 const int* __restrict__ dst,
                                                 int* __restrict__ gtail,
                                                 int2* __restrict__ bucketed,
                                                 int* __restrict__ cnt,
                                                 int N, int E, int NB, int seg, int GB) {
    __shared__ __align__(16) char smem[GEMM_SMEM];
    const int t = threadIdx.x;

    if ((int)blockIdx.x < GB) {
        // ---- gemm1: OUT[N,64] = X[N,128] @ W1[128,64], bf16 out ----
        float* xs = (float*)smem;                    // 64 x 36
        float* Wp = (float*)(smem + 64 * KCP * 4);   // 32 x 64
        const int row0 = blockIdx.x * 64;
        const int c4 = (t & 15) * 4;
        const int r4 = (t >> 4) * 4;
        float acc[4][4] = {};

        for (int k0 = 0; k0 < 128; k0 += KC) {
            const float4* W4 = reinterpret_cast<const float4*>(W + k0 * 64);
            #pragma unroll
            for (int i = t; i < KC * 16; i += 256)
                reinterpret_cast<float4*>(Wp)[i] = W4[i];
            #pragma unroll
            for (int i = t; i < 64 * 8; i += 256) {
                int r = i >> 3, kq = i & 7;
                int m = row0 + r;
                float4 v = make_float4(0.f, 0.f, 0.f, 0.f);
                if (m < N) v = *reinterpret_cast<const float4*>(&X[(size_t)m * 128 + k0 + kq * 4]);
                *reinterpret_cast<float4*>(&xs[r * KCP + kq * 4]) = v;
            }
            __syncthreads();

            for (int k = 0; k < KC; k += 4) {
                float4 A[4], B[4];
                #pragma unroll
                for (int i = 0; i < 4; i++)
                    A[i] = *reinterpret_cast<const float4*>(&xs[(r4 + i) * KCP + k]);
                #pragma unroll
                for (int kk = 0; kk < 4; kk++)
                    B[kk] = *reinterpret_cast<const float4*>(&Wp[(k + kk) * 64 + c4]);
                const float* Af = reinterpret_cast<const float*>(A);
                const float* Bf = reinterpret_cast<const float*>(B);
                #pragma unroll
                for (int i = 0; i < 4; i++)
                    #pragma unroll
                    for (int kk = 0; kk < 4; kk++) {
                        float av = Af[i * 4 + kk];
                        #pragma unroll
                        for (int j = 0; j < 4; j++)
                            acc[i][j] = fmaf(av, Bf[kk * 4 + j], acc[i][j]);
                    }
            }
            __syncthreads();
        }
        #pragma unroll
        for (int i = 0; i < 4; i++) {
            int m = row0 + r4 + i;
            if (m >= N) continue;
            ushort4 o;
            o.x = f2bf(acc[i][0]); o.y = f2bf(acc[i][1]);
            o.z = f2bf(acc[i][2]); o.w = f2bf(acc[i][3]);
            *reinterpret_cast<ushort4*>(&OUT[(size_t)m * 64 + c4]) = o;
        }
    } else {
        // ---- bin: 98 buckets (dst>>10); LDS histogram -> run reservation -> int2 records ----
        int* hist = (int*)smem;
        int* base = hist + 128;
        const int bid = blockIdx.x - GB;
        const int nbin = gridDim.x - GB;
        for (int i = bid * 256 + t; i < N; i += nbin * 256) cnt[i] = 0;

        const int b0 = bid * seg;
        const int b1 = min(b0 + seg, E);
        for (int i = t; i < NB; i += 256) hist[i] = 0;
        __syncthreads();
        for (int e = b0 + t; e < b1; e += 256)
            atomicAdd(&hist[dst[e] >> NBSHIFT], 1);
        __syncthreads();
        for (int i = t; i < NB; i += 256) {
            int h = hist[i];
            base[i] = h ? atomicAdd(&gtail[i], h) : 0;
            hist[i] = 0;
        }
        __syncthreads();
        for (int e = b0 + t; e < b1; e += 256) {
            int d = dst[e];
            int b = d >> NBSHIFT;
            int idx = base[b] + atomicAdd(&hist[b], 1);
            if (idx < BCAP) bucketed[(size_t)b * BCAP + idx] = make_int2(src[e], d);
        }
    }
}

// ---------------- scatter within L2-resident bucket slice + dinv ----------------

__global__ __launch_bounds__(512) void scatter_csr(const int2* __restrict__ bucketed,
                                                   const int* __restrict__ gtail,
                                                   int* __restrict__ cnt,
                                                   int* __restrict__ csr_src,
                                                   float* __restrict__ dinv, int N) {
    const int b = blockIdx.x;
    int n = gtail[b]; if (n > BCAP) n = BCAP;
    const int2* p = bucketed + (size_t)b * BCAP;
    for (int i = threadIdx.x; i < n; i += 512) {
        int2 e = p[i];
        int slot = atomicAdd(&cnt[e.y], 1);
        if (slot < CAP) csr_src[e.y * CAP + slot] = e.x;
    }
    __syncthreads();
    const int v0 = b << NBSHIFT;
    for (int i = threadIdx.x; i < (1 << NBSHIFT); i += 512) {
        int v = v0 + i;
        if (v < N) {
            int cv = atomicAdd(&cnt[v], 0);
            dinv[v] = rsqrtf((float)cv + 1.0f);
        }
    }
}

// ---------------- gemm2: hw2[N,48] = h[N,64] @ W2[64,47] (col 47 zero), bf16 out ----------------

__global__ __launch_bounds__(256) void gemm2_tiled(const float* __restrict__ X,
                                                   const float* __restrict__ W,
                                                   u16* __restrict__ OUT, int N) {
    __shared__ __align__(16) char smem[GEMM_SMEM];
    float* xs = (float*)smem;                    // 64 x 36
    float* Wp = (float*)(smem + 64 * KCP * 4);   // 32 x 64
    const int t = threadIdx.x;
    const int row0 = blockIdx.x * 64;
    const int c4 = (t & 15) * 4;
    const int r4 = (t >> 4) * 4;
    float acc[4][4] = {};

    for (int k0 = 0; k0 < 64; k0 += KC) {
        for (int i = t; i < KC * 64; i += 256) {
            int k = i >> 6, c = i & 63;
            Wp[i] = (c < 47) ? W[(k0 + k) * 47 + c] : 0.f;
        }
        #pragma unroll
        for (int i = t; i < 64 * 8; i += 256) {
            int r = i >> 3, kq = i & 7;
            int m = row0 + r;
            float4 v = make_float4(0.f, 0.f, 0.f, 0.f);
            if (m < N) v = *reinterpret_cast<const float4*>(&X[(size_t)m * 64 + k0 + kq * 4]);
            *reinterpret_cast<float4*>(&xs[r * KCP + kq * 4]) = v;
        }
        __syncthreads();

        for (int k = 0; k < KC; k += 4) {
            float4 A[4], B[4];
            #pragma unroll
            for (int i = 0; i < 4; i++)
                A[i] = *reinterpret_cast<const float4*>(&xs[(r4 + i) * KCP + k]);
            #pragma unroll
            for (int kk = 0; kk < 4; kk++)
                B[kk] = *reinterpret_cast<const float4*>(&Wp[(k + kk) * 64 + c4]);
            const float* Af = reinterpret_cast<const float*>(A);
            const float* Bf = reinterpret_cast<const float*>(B);
            #pragma unroll
            for (int i = 0; i < 4; i++)
                #pragma unroll
                for (int kk = 0; kk < 4; kk++) {
                    float av = Af[i * 4 + kk];
                    #pragma unroll
                    for (int j = 0; j < 4; j++)
                        acc[i][j] = fmaf(av, Bf[kk * 4 + j], acc[i][j]);
                }
        }
        __syncthreads();
    }
    if (c4 >= 48) return;   // cols 48..63 don't exist in the 48-wide buffer
    #pragma unroll
    for (int i = 0; i < 4; i++) {
        int m = row0 + r4 + i;
        if (m >= N) continue;
        ushort4 o;
        o.x = f2bf(acc[i][0]); o.y = f2bf(acc[i][1]);
        o.z = f2bf(acc[i][2]); o.w = f2bf(acc[i][3]);
        *reinterpret_cast<ushort4*>(&OUT[(size_t)m * 48 + c4]) = o;
    }
}

// 8 bf16 (uint4) * w accumulated into acc[8]
__device__ __forceinline__ void fma_bf8(uint4 q, float w, float* acc) {
    acc[0] = fmaf(__uint_as_float(q.x << 16),          w, acc[0]);
    acc[1] = fmaf(__uint_as_float(q.x & 0xffff0000u),  w, acc[1]);
    acc[2] = fmaf(__uint_as_float(q.y << 16),          w, acc[2]);
    acc[3] = fmaf(__uint_as_float(q.y & 0xffff0000u),  w, acc[3]);
    acc[4] = fmaf(__uint_as_float(q.z << 16),          w, acc[4]);
    acc[5] = fmaf(__uint_as_float(q.z & 0xffff0000u),  w, acc[5]);
    acc[6] = fmaf(__uint_as_float(q.w << 16),          w, acc[6]);
    acc[7] = fmaf(__uint_as_float(q.w & 0xffff0000u),  w, acc[7]);
}

// ---------------- layer-1 aggregation: h = relu(agg + xw/deg + b1), F=64 ----------------
// 2 nodes/wave (half-wave = node); predicated gathers; lazy rawB. (r14 form)

__global__ __launch_bounds__(256, 4) void agg1_relu(const u16* __restrict__ xw,
                                                    const int* __restrict__ csr_src,
                                                    const int* __restrict__ cnt,
                                                    const float* __restrict__ dinv,
                                                    const float* __restrict__ bias,
                                                    float* __restrict__ h, int N) {
    const int wid = (blockIdx.x * 256 + threadIdx.x) >> 6;
    const int lane = threadIdx.x & 63;
    const int v = wid * 2 + (lane >> 5);
    if (wid * 2 >= N) return;
    const bool okv = v < N;
    const int vs = okv ? v : 0;
    const int hl = lane & 31;
    int c = okv ? cnt[vs] : 0; if (c > CAP - 1) c = CAP - 1;
    const float dv = okv ? dinv[vs] : 0.f;
    int rawA = csr_src[vs * CAP + hl];
    int sA; float wA;
    if (hl < c)        { sA = rawA; wA = dinv[sA] * dv; }
    else if (hl == c)  { sA = vs;   wA = dv * dv; }
    else               { sA = 0;    wA = 0.f; }

    int ce = c + 1;
    int cemax = max(ce, __shfl_xor(ce, 32));
    const int r = hl >> 3, b = hl & 7;
    const int base = lane & 32;
    float acc[8] = {};

    {
        int s8[8]; float w8[8];
        #pragma unroll
        for (int u = 0; u < 8; u++) {
            int e = u * 4 + r;
            s8[u] = __shfl(sA, base + e);
            w8[u] = __shfl(wA, base + e);
        }
        uint4 q8[8];
        #pragma unroll
        for (int u = 0; u < 8; u++)
            if (u * 4 < cemax)
                q8[u] = *reinterpret_cast<const uint4*>(&xw[(size_t)s8[u] * 64 + b * 8]);
        #pragma unroll
        for (int u = 0; u < 8; u++)
            if (u * 4 < cemax) fma_bf8(q8[u], w8[u], acc);
    }
    if (cemax > 32) {   // rare (deg >= 32): slots 32..63, csr read deferred to here
        int rawB = csr_src[vs * CAP + 32 + hl];
        int hl32 = hl + 32;
        int sB; float wB;
        if (hl32 < c)       { sB = rawB; wB = dinv[sB] * dv; }
        else if (hl32 == c) { sB = vs;   wB = dv * dv; }
        else                { sB = 0;    wB = 0.f; }
        int s8[8]; float w8[8];
        #pragma unroll
        for (int u = 0; u < 8; u++) {
            int e = u * 4 + r;
            s8[u] = __shfl(sB, base + e);
            w8[u] = __shfl(wB, base + e);
        }
        uint4 q8[8];
        #pragma unroll
        for (int u = 0; u < 8; u++)
            if (32 + u * 4 < cemax)
                q8[u] = *reinterpret_cast<const uint4*>(&xw[(size_t)s8[u] * 64 + b * 8]);
        #pragma unroll
        for (int u = 0; u < 8; u++)
            if (32 + u * 4 < cemax) fma_bf8(q8[u], w8[u], acc);
    }

    #pragma unroll
    for (int u = 0; u < 8; u++) {
        acc[u] += __shfl_xor(acc[u], 8);
        acc[u] += __shfl_xor(acc[u], 16);
    }
    if (r == 0 && okv) {
        float o[8];
        #pragma unroll
        for (int u = 0; u < 8; u++)
            o[u] = fmaxf(acc[u] + bias[b * 8 + u], 0.f);
        float* dstp = &h[(size_t)v * 64 + b * 8];
        *reinterpret_cast<float4*>(dstp)     = make_float4(o[0], o[1], o[2], o[3]);
        *reinterpret_cast<float4*>(dstp + 4) = make_float4(o[4], o[5], o[6], o[7]);
    }
}

// ---------------- layer-2 aggregation fused with log_softmax, rows 48 bf16 (96B) ----------------
// Feature-blocks b<6 are real (f = b*8+u, valid f < 47); b in {6,7} clamp their
// load offset to 0 — their vals are masked to -inf by the f<47 guard.

__global__ __launch_bounds__(256, 4) void agg2_lsm(const u16* __restrict__ hw,
                                                   const int* __restrict__ csr_src,
                                                   const int* __restrict__ cnt,
                                                   const float* __restrict__ dinv,
                                                   const float* __restrict__ bias,
                                                   float* __restrict__ out, int N) {
    const int wid = (blockIdx.x * 256 + threadIdx.x) >> 6;
    const int lane = threadIdx.x & 63;
    const int v = wid * 2 + (lane >> 5);
    if (wid * 2 >= N) return;
    const bool okv = v < N;
    const int vs = okv ? v : 0;
    const int hl = lane & 31;
    int c = okv ? cnt[vs] : 0; if (c > CAP - 1) c = CAP - 1;
    const float dv = okv ? dinv[vs] : 0.f;
    int rawA = csr_src[vs * CAP + hl];
    int sA; float wA;
    if (hl < c)        { sA = rawA; wA = dinv[sA] * dv; }
    else if (hl == c)  { sA = vs;   wA = dv * dv; }
    else               { sA = 0;    wA = 0.f; }

    int ce = c + 1;
    int cemax = max(ce, __shfl_xor(ce, 32));
    const int r = hl >> 3, b = hl & 7;
    const int boff = (b < 6) ? b * 8 : 0;   // load offset within 48-wide row
    const int base = lane & 32;
    float acc[8] = {};

    {
        int s8[8]; float w8[8];
        #pragma unroll
        for (int u = 0; u < 8; u++) {
            int e = u * 4 + r;
            s8[u] = __shfl(sA, base + e);
            w8[u] = __shfl(wA, base + e);
        }
        uint4 q8[8];
        #pragma unroll
        for (int u = 0; u < 8; u++)
            if (u * 4 < cemax)
                q8[u] = *reinterpret_cast<const uint4*>(&hw[(size_t)s8[u] * 48 + boff]);
        #pragma unroll
        for (int u = 0; u < 8; u++)
            if (u * 4 < cemax) fma_bf8(q8[u], w8[u], acc);
    }
    if (cemax > 32) {
        int rawB = csr_src[vs * CAP + 32 + hl];
        int hl32 = hl + 32;
        int sB; float wB;
        if (hl32 < c)       { sB = rawB; wB = dinv[sB] * dv; }
        else if (hl32 == c) { sB = vs;   wB = dv * dv; }
        else                { sB = 0;    wB = 0.f; }
        int s8[8]; float w8[8];
        #pragma unroll
        for (int u = 0; u < 8; u++) {
            int e = u * 4 + r;
            s8[u] = __shfl(sB, base + e);
            w8[u] = __shfl(wB, base + e);
        }
        uint4 q8[8];
        #pragma unroll
        for (int u = 0; u < 8; u++)
            if (32 + u * 4 < cemax)
                q8[u] = *reinterpret_cast<const uint4*>(&hw[(size_t)s8[u] * 48 + boff]);
        #pragma unroll
        for (int u = 0; u < 8; u++)
            if (32 + u * 4 < cemax) fma_bf8(q8[u], w8[u], acc);
    }

    #pragma unroll
    for (int u = 0; u < 8; u++) {
        acc[u] += __shfl_xor(acc[u], 8);
        acc[u] += __shfl_xor(acc[u], 16);
    }
    const int f0 = b * 8;
    float val[8];
    #pragma unroll
    for (int u = 0; u < 8; u++) {
        int f = f0 + u;
        val[u] = (f < 47) ? acc[u] + bias[f] : -INFINITY;
    }
    float m = val[0];
    #pragma unroll
    for (int u = 1; u < 8; u++) m = fmaxf(m, val[u]);
    m = fmaxf(m, __shfl_xor(m, 1));
    m = fmaxf(m, __shfl_xor(m, 2));
    m = fmaxf(m, __shfl_xor(m, 4));
    float s = 0.f;
    #pragma unroll
    for (int u = 0; u < 8; u++)
        s += (f0 + u < 47) ? __expf(val[u] - m) : 0.f;
    s += __shfl_xor(s, 1);
    s += __shfl_xor(s, 2);
    s += __shfl_xor(s, 4);
    float ls = m + __logf(s);
    if (r == 0 && okv) {
        #pragma unroll
        for (int u = 0; u < 8; u++) {
            int f = f0 + u;
            if (f < 47) out[(size_t)v * 47 + f] = val[u] - ls;
        }
    }
}

// ---------------- launch ----------------

extern "C" void kernel_launch(void* const* d_in, const int* in_sizes, int n_in,
                              void* d_out, int out_size, void* d_ws, size_t ws_size,
                              hipStream_t stream) {
    const float* x  = (const float*)d_in[0];
    const int*   ei = (const int*)d_in[1];
    const float* W1 = (const float*)d_in[2];
    const float* b1 = (const float*)d_in[3];
    const float* W2 = (const float*)d_in[4];
    const float* b2 = (const float*)d_in[5];
    float* out = (float*)d_out;

    const int N = in_sizes[0] / 128;
    const int E = in_sizes[1] / 2;
    const int* src = ei;
    const int* dst = ei + E;
    const int NB = ((N - 1) >> NBSHIFT) + 1;   // 98 for N=100000

    char* ws = (char*)d_ws;
    size_t off = 0;
    auto alloc = [&](size_t bytes) {
        void* p = ws + off;
        off += (bytes + 255) & ~(size_t)255;
        return p;
    };
    int*   cnt     = (int*)  alloc((size_t)N * 4);
    int*   gtail   = (int*)  alloc((size_t)128 * 4);
    float* dinv    = (float*)alloc((size_t)N * 4);
    int*   csr_src = (int*)  alloc((size_t)N * CAP * 4);
    u16*   xw1     = (u16*)  alloc((size_t)N * 64 * 2);
    float* hbuf    = (float*)alloc((size_t)N * 64 * 4);
    u16*   hw2     = (u16*)  alloc((size_t)N * 48 * 2);   // bf16 [N,48], 96B rows

    int2* bucketed = (int2*)hbuf;  // 16.1MB <= 25.6MB; dead before agg1 writes h

    hipMemsetAsync(gtail, 0, 128 * 4, stream);

    const int GB = (N + 63) / 64;
    const int gridA = 512;
    const int seg = (E + gridA - 1) / gridA;
    gemm1_bin<<<GB + gridA, 256, 0, stream>>>(x, W1, xw1, src, dst, gtail, bucketed,
                                              cnt, N, E, NB, seg, GB);
    scatter_csr<<<NB, 512, 0, stream>>>(bucketed, gtail, cnt, csr_src, dinv, N);
    agg1_relu<<<(N + 7) / 8, 256, 0, stream>>>(xw1, csr_src, cnt, dinv, b1, hbuf, N);
    gemm2_tiled<<<(N + 63) / 64, 256, 0, stream>>>(hbuf, W2, hw2, N);
    agg2_lsm<<<(N + 7) / 8, 256, 0, stream>>>(hw2, csr_src, cnt, dinv, b2, out, N);
}

// Round 16
// 285.517 us; speedup vs baseline: 1.0421x; 1.0421x over previous
//
#include <hip/hip_runtime.h>
#include <hip/hip_bf16.h>
#include <math.h>

// GCN 2-layer: out = log_softmax( GCN2( relu( GCN1(x) ) ) )
// GCNConv: out = D^-1/2 A D^-1/2 (X W) + (X W)/deg + b,  deg = 1 + indeg(dst)
//
// Round 16: exact r14 structure (best, 288.5us; r15's 96B rows broke line
// alignment -> FETCH +25%, reverted) + ONE change: h stored as bf16 [N,64]
// (128B aligned rows). agg1 write 25.6->12.8MB, gemm2 read 25.6->12.8MB;
// gemm2 stages bf16->fp32 into LDS, fp32 compute unchanged.

#define CAP 64
#define NBSHIFT 10
#define BCAP 20480
typedef unsigned short u16;

__device__ __forceinline__ u16 f2bf(float f) {
    __hip_bfloat16 h = __float2bfloat16(f);
    return *reinterpret_cast<u16*>(&h);
}
__device__ __forceinline__ float bf2f(u16 u) {
    return __uint_as_float(((unsigned)u) << 16);
}

// ---------------- fused: gemm1 (blocks [0,GB)) || bin_edges (blocks [GB,GB+512)) ----------------
// gemm1: K=128 in 4 chunks of 32. LDS/chunk: xs 64x36 fp32 + Wp 32x64 fp32 = 17408 B.

#define KC 32
#define KCP 36
#define GEMM_SMEM (64 * KCP * 4 + KC * 64 * 4)   // 17408 B

__global__ __launch_bounds__(256) void gemm1_bin(const float* __restrict__ X,
                                                 const float* __restrict__ W,
                                                 u16* __restrict__ OUT,
                                                 const int* __restrict__ src,
                                                 const int* __restrict__ dst,
                                                 int* __restrict__ gtail,
                                                 int2* __restrict__ bucketed,
                                                 int* __restrict__ cnt,
                                                 int N, int E, int NB, int seg, int GB) {
    __shared__ __align__(16) char smem[GEMM_SMEM];
    const int t = threadIdx.x;

    if ((int)blockIdx.x < GB) {
        // ---- gemm1: OUT[N,64] = X[N,128] @ W1[128,64], bf16 out ----
        float* xs = (float*)smem;                    // 64 x 36
        float* Wp = (float*)(smem + 64 * KCP * 4);   // 32 x 64
        const int row0 = blockIdx.x * 64;
        const int c4 = (t & 15) * 4;
        const int r4 = (t >> 4) * 4;
        float acc[4][4] = {};

        for (int k0 = 0; k0 < 128; k0 += KC) {
            const float4* W4 = reinterpret_cast<const float4*>(W + k0 * 64);
            #pragma unroll
            for (int i = t; i < KC * 16; i += 256)
                reinterpret_cast<float4*>(Wp)[i] = W4[i];
            #pragma unroll
            for (int i = t; i < 64 * 8; i += 256) {
                int r = i >> 3, kq = i & 7;
                int m = row0 + r;
                float4 v = make_float4(0.f, 0.f, 0.f, 0.f);
                if (m < N) v = *reinterpret_cast<const float4*>(&X[(size_t)m * 128 + k0 + kq * 4]);
                *reinterpret_cast<float4*>(&xs[r * KCP + kq * 4]) = v;
            }
            __syncthreads();

            for (int k = 0; k < KC; k += 4) {
                float4 A[4], B[4];
                #pragma unroll
                for (int i = 0; i < 4; i++)
                    A[i] = *reinterpret_cast<const float4*>(&xs[(r4 + i) * KCP + k]);
                #pragma unroll
                for (int kk = 0; kk < 4; kk++)
                    B[kk] = *reinterpret_cast<const float4*>(&Wp[(k + kk) * 64 + c4]);
                const float* Af = reinterpret_cast<const float*>(A);
                const float* Bf = reinterpret_cast<const float*>(B);
                #pragma unroll
                for (int i = 0; i < 4; i++)
                    #pragma unroll
                    for (int kk = 0; kk < 4; kk++) {
                        float av = Af[i * 4 + kk];
                        #pragma unroll
                        for (int j = 0; j < 4; j++)
                            acc[i][j] = fmaf(av, Bf[kk * 4 + j], acc[i][j]);
                    }
            }
            __syncthreads();
        }
        #pragma unroll
        for (int i = 0; i < 4; i++) {
            int m = row0 + r4 + i;
            if (m >= N) continue;
            ushort4 o;
            o.x = f2bf(acc[i][0]); o.y = f2bf(acc[i][1]);
            o.z = f2bf(acc[i][2]); o.w = f2bf(acc[i][3]);
            *reinterpret_cast<ushort4*>(&OUT[(size_t)m * 64 + c4]) = o;
        }
    } else {
        // ---- bin: 98 buckets (dst>>10); LDS histogram -> run reservation -> int2 records ----
        int* hist = (int*)smem;
        int* base = hist + 128;
        const int bid = blockIdx.x - GB;
        const int nbin = gridDim.x - GB;
        for (int i = bid * 256 + t; i < N; i += nbin * 256) cnt[i] = 0;

        const int b0 = bid * seg;
        const int b1 = min(b0 + seg, E);
        for (int i = t; i < NB; i += 256) hist[i] = 0;
        __syncthreads();
        for (int e = b0 + t; e < b1; e += 256)
            atomicAdd(&hist[dst[e] >> NBSHIFT], 1);
        __syncthreads();
        for (int i = t; i < NB; i += 256) {
            int h = hist[i];
            base[i] = h ? atomicAdd(&gtail[i], h) : 0;
            hist[i] = 0;
        }
        __syncthreads();
        for (int e = b0 + t; e < b1; e += 256) {
            int d = dst[e];
            int b = d >> NBSHIFT;
            int idx = base[b] + atomicAdd(&hist[b], 1);
            if (idx < BCAP) bucketed[(size_t)b * BCAP + idx] = make_int2(src[e], d);
        }
    }
}

// ---------------- scatter within L2-resident bucket slice + dinv ----------------

__global__ __launch_bounds__(512) void scatter_csr(const int2* __restrict__ bucketed,
                                                   const int* __restrict__ gtail,
                                                   int* __restrict__ cnt,
                                                   int* __restrict__ csr_src,
                                                   float* __restrict__ dinv, int N) {
    const int b = blockIdx.x;
    int n = gtail[b]; if (n > BCAP) n = BCAP;
    const int2* p = bucketed + (size_t)b * BCAP;
    for (int i = threadIdx.x; i < n; i += 512) {
        int2 e = p[i];
        int slot = atomicAdd(&cnt[e.y], 1);
        if (slot < CAP) csr_src[e.y * CAP + slot] = e.x;
    }
    __syncthreads();
    const int v0 = b << NBSHIFT;
    for (int i = threadIdx.x; i < (1 << NBSHIFT); i += 512) {
        int v = v0 + i;
        if (v < N) {
            int cv = atomicAdd(&cnt[v], 0);
            dinv[v] = rsqrtf((float)cv + 1.0f);
        }
    }
}

// ---------------- gemm2: hw2[N,64] = h[N,64](bf16) @ W2[64,47] (zero-padded), bf16 out --------

__global__ __launch_bounds__(256) void gemm2_tiled(const u16* __restrict__ X,
                                                   const float* __restrict__ W,
                                                   u16* __restrict__ OUT, int N) {
    __shared__ __align__(16) char smem[GEMM_SMEM];
    float* xs = (float*)smem;                    // 64 x 36
    float* Wp = (float*)(smem + 64 * KCP * 4);   // 32 x 64
    const int t = threadIdx.x;
    const int row0 = blockIdx.x * 64;
    const int c4 = (t & 15) * 4;
    const int r4 = (t >> 4) * 4;
    float acc[4][4] = {};

    for (int k0 = 0; k0 < 64; k0 += KC) {
        for (int i = t; i < KC * 64; i += 256) {
            int k = i >> 6, c = i & 63;
            Wp[i] = (c < 47) ? W[(k0 + k) * 47 + c] : 0.f;
        }
        // stage X chunk: bf16 rows, 32 bf16 (64B) per row per chunk = 4 uint4
        {
            int i = t;                                   // 64 rows x 4 quads = 256
            int r = i >> 2, kq = i & 3;
            int m = row0 + r;
            uint4 q = make_uint4(0u, 0u, 0u, 0u);
            if (m < N) q = *reinterpret_cast<const uint4*>(&X[(size_t)m * 64 + k0 + kq * 8]);
            float f0o = bf2f(q.x & 0xffffu), f1 = bf2f(q.x >> 16);
            float f2 = bf2f(q.y & 0xffffu), f3 = bf2f(q.y >> 16);
            float f4 = bf2f(q.z & 0xffffu), f5 = bf2f(q.z >> 16);
            float f6 = bf2f(q.w & 0xffffu), f7 = bf2f(q.w >> 16);
            float* dstp = &xs[r * KCP + kq * 8];
            *reinterpret_cast<float4*>(dstp)     = make_float4(f0o, f1, f2, f3);
            *reinterpret_cast<float4*>(dstp + 4) = make_float4(f4, f5, f6, f7);
        }
        __syncthreads();

        for (int k = 0; k < KC; k += 4) {
            float4 A[4], B[4];
            #pragma unroll
            for (int i = 0; i < 4; i++)
                A[i] = *reinterpret_cast<const float4*>(&xs[(r4 + i) * KCP + k]);
            #pragma unroll
            for (int kk = 0; kk < 4; kk++)
                B[kk] = *reinterpret_cast<const float4*>(&Wp[(k + kk) * 64 + c4]);
            const float* Af = reinterpret_cast<const float*>(A);
            const float* Bf = reinterpret_cast<const float*>(B);
            #pragma unroll
            for (int i = 0; i < 4; i++)
                #pragma unroll
                for (int kk = 0; kk < 4; kk++) {
                    float av = Af[i * 4 + kk];
                    #pragma unroll
                    for (int j = 0; j < 4; j++)
                        acc[i][j] = fmaf(av, Bf[kk * 4 + j], acc[i][j]);
                }
        }
        __syncthreads();
    }
    #pragma unroll
    for (int i = 0; i < 4; i++) {
        int m = row0 + r4 + i;
        if (m >= N) continue;
        ushort4 o;
        o.x = f2bf(acc[i][0]); o.y = f2bf(acc[i][1]);
        o.z = f2bf(acc[i][2]); o.w = f2bf(acc[i][3]);
        *reinterpret_cast<ushort4*>(&OUT[(size_t)m * 64 + c4]) = o;
    }
}

// 8 bf16 (uint4) * w accumulated into acc[8]
__device__ __forceinline__ void fma_bf8(uint4 q, float w, float* acc) {
    acc[0] = fmaf(__uint_as_float(q.x << 16),          w, acc[0]);
    acc[1] = fmaf(__uint_as_float(q.x & 0xffff0000u),  w, acc[1]);
    acc[2] = fmaf(__uint_as_float(q.y << 16),          w, acc[2]);
    acc[3] = fmaf(__uint_as_float(q.y & 0xffff0000u),  w, acc[3]);
    acc[4] = fmaf(__uint_as_float(q.z << 16),          w, acc[4]);
    acc[5] = fmaf(__uint_as_float(q.z & 0xffff0000u),  w, acc[5]);
    acc[6] = fmaf(__uint_as_float(q.w << 16),          w, acc[6]);
    acc[7] = fmaf(__uint_as_float(q.w & 0xffff0000u),  w, acc[7]);
}

// ---------------- layer-1 aggregation: h = relu(agg + xw/deg + b1), F=64, bf16 out -------------
// 2 nodes/wave (half-wave = node); predicated gathers; lazy rawB. (r14 form)

__global__ __launch_bounds__(256, 4) void agg1_relu(const u16* __restrict__ xw,
                                                    const int* __restrict__ csr_src,
                                                    const int* __restrict__ cnt,
                                                    const float* __restrict__ dinv,
                                                    const float* __restrict__ bias,
                                                    u16* __restrict__ h, int N) {
    const int wid = (blockIdx.x * 256 + threadIdx.x) >> 6;
    const int lane = threadIdx.x & 63;
    const int v = wid * 2 + (lane >> 5);
    if (wid * 2 >= N) return;
    const bool okv = v < N;
    const int vs = okv ? v : 0;
    const int hl = lane & 31;
    int c = okv ? cnt[vs] : 0; if (c > CAP - 1) c = CAP - 1;
    const float dv = okv ? dinv[vs] : 0.f;
    int rawA = csr_src[vs * CAP + hl];
    int sA; float wA;
    if (hl < c)        { sA = rawA; wA = dinv[sA] * dv; }
    else if (hl == c)  { sA = vs;   wA = dv * dv; }
    else               { sA = 0;    wA = 0.f; }

    int ce = c + 1;
    int cemax = max(ce, __shfl_xor(ce, 32));
    const int r = hl >> 3, b = hl & 7;
    const int base = lane & 32;
    float acc[8] = {};

    {
        int s8[8]; float w8[8];
        #pragma unroll
        for (int u = 0; u < 8; u++) {
            int e = u * 4 + r;
            s8[u] = __shfl(sA, base + e);
            w8[u] = __shfl(wA, base + e);
        }
        uint4 q8[8];
        #pragma unroll
        for (int u = 0; u < 8; u++)
            if (u * 4 < cemax)
                q8[u] = *reinterpret_cast<const uint4*>(&xw[(size_t)s8[u] * 64 + b * 8]);
        #pragma unroll
        for (int u = 0; u < 8; u++)
            if (u * 4 < cemax) fma_bf8(q8[u], w8[u], acc);
    }
    if (cemax > 32) {   // rare (deg >= 32): slots 32..63, csr read deferred to here
        int rawB = csr_src[vs * CAP + 32 + hl];
        int hl32 = hl + 32;
        int sB; float wB;
        if (hl32 < c)       { sB = rawB; wB = dinv[sB] * dv; }
        else if (hl32 == c) { sB = vs;   wB = dv * dv; }
        else                { sB = 0;    wB = 0.f; }
        int s8[8]; float w8[8];
        #pragma unroll
        for (int u = 0; u < 8; u++) {
            int e = u * 4 + r;
            s8[u] = __shfl(sB, base + e);
            w8[u] = __shfl(wB, base + e);
        }
        uint4 q8[8];
        #pragma unroll
        for (int u = 0; u < 8; u++)
            if (32 + u * 4 < cemax)
                q8[u] = *reinterpret_cast<const uint4*>(&xw[(size_t)s8[u] * 64 + b * 8]);
        #pragma unroll
        for (int u = 0; u < 8; u++)
            if (32 + u * 4 < cemax) fma_bf8(q8[u], w8[u], acc);
    }

    #pragma unroll
    for (int u = 0; u < 8; u++) {
        acc[u] += __shfl_xor(acc[u], 8);
        acc[u] += __shfl_xor(acc[u], 16);
    }
    if (r == 0 && okv) {
        ushort4 oA, oB;
        oA.x = f2bf(fmaxf(acc[0] + bias[b * 8 + 0], 0.f));
        oA.y = f2bf(fmaxf(acc[1] + bias[b * 8 + 1], 0.f));
        oA.z = f2bf(fmaxf(acc[2] + bias[b * 8 + 2], 0.f));
        oA.w = f2bf(fmaxf(acc[3] + bias[b * 8 + 3], 0.f));
        oB.x = f2bf(fmaxf(acc[4] + bias[b * 8 + 4], 0.f));
        oB.y = f2bf(fmaxf(acc[5] + bias[b * 8 + 5], 0.f));
        oB.z = f2bf(fmaxf(acc[6] + bias[b * 8 + 6], 0.f));
        oB.w = f2bf(fmaxf(acc[7] + bias[b * 8 + 7], 0.f));
        u16* dstp = &h[(size_t)v * 64 + b * 8];
        *reinterpret_cast<ushort4*>(dstp)     = oA;
        *reinterpret_cast<ushort4*>(dstp + 4) = oB;
    }
}

// ---------------- layer-2 aggregation fused with log_softmax, F=47 (rows padded to 64) ----------

__global__ __launch_bounds__(256, 4) void agg2_lsm(const u16* __restrict__ hw,
                                                   const int* __restrict__ csr_src,
                                                   const int* __restrict__ cnt,
                                                   const float* __restrict__ dinv,
                                                   const float* __restrict__ bias,
                                                   float* __restrict__ out, int N) {
    const int wid = (blockIdx.x * 256 + threadIdx.x) >> 6;
    const int lane = threadIdx.x & 63;
    const int v = wid * 2 + (lane >> 5);
    if (wid * 2 >= N) return;
    const bool okv = v < N;
    const int vs = okv ? v : 0;
    const int hl = lane & 31;
    int c = okv ? cnt[vs] : 0; if (c > CAP - 1) c = CAP - 1;
    const float dv = okv ? dinv[vs] : 0.f;
    int rawA = csr_src[vs * CAP + hl];
    int sA; float wA;
    if (hl < c)        { sA = rawA; wA = dinv[sA] * dv; }
    else if (hl == c)  { sA = vs;   wA = dv * dv; }
    else               { sA = 0;    wA = 0.f; }

    int ce = c + 1;
    int cemax = max(ce, __shfl_xor(ce, 32));
    const int r = hl >> 3, b = hl & 7;
    const int base = lane & 32;
    float acc[8] = {};

    {
        int s8[8]; float w8[8];
        #pragma unroll
        for (int u = 0; u < 8; u++) {
            int e = u * 4 + r;
            s8[u] = __shfl(sA, base + e);
            w8[u] = __shfl(wA, base + e);
        }
        uint4 q8[8];
        #pragma unroll
        for (int u = 0; u < 8; u++)
            if (u * 4 < cemax)
                q8[u] = *reinterpret_cast<const uint4*>(&hw[(size_t)s8[u] * 64 + b * 8]);
        #pragma unroll
        for (int u = 0; u < 8; u++)
            if (u * 4 < cemax) fma_bf8(q8[u], w8[u], acc);
    }
    if (cemax > 32) {
        int rawB = csr_src[vs * CAP + 32 + hl];
        int hl32 = hl + 32;
        int sB; float wB;
        if (hl32 < c)       { sB = rawB; wB = dinv[sB] * dv; }
        else if (hl32 == c) { sB = vs;   wB = dv * dv; }
        else                { sB = 0;    wB = 0.f; }
        int s8[8]; float w8[8];
        #pragma unroll
        for (int u = 0; u < 8; u++) {
            int e = u * 4 + r;
            s8[u] = __shfl(sB, base + e);
            w8[u] = __shfl(wB, base + e);
        }
        uint4 q8[8];
        #pragma unroll
        for (int u = 0; u < 8; u++)
            if (32 + u * 4 < cemax)
                q8[u] = *reinterpret_cast<const uint4*>(&hw[(size_t)s8[u] * 64 + b * 8]);
        #pragma unroll
        for (int u = 0; u < 8; u++)
            if (32 + u * 4 < cemax) fma_bf8(q8[u], w8[u], acc);
    }

    #pragma unroll
    for (int u = 0; u < 8; u++) {
        acc[u] += __shfl_xor(acc[u], 8);
        acc[u] += __shfl_xor(acc[u], 16);
    }
    const int f0 = b * 8;
    float val[8];
    #pragma unroll
    for (int u = 0; u < 8; u++) {
        int f = f0 + u;
        val[u] = (f < 47) ? acc[u] + bias[f] : -INFINITY;
    }
    float m = val[0];
    #pragma unroll
    for (int u = 1; u < 8; u++) m = fmaxf(m, val[u]);
    m = fmaxf(m, __shfl_xor(m, 1));
    m = fmaxf(m, __shfl_xor(m, 2));
    m = fmaxf(m, __shfl_xor(m, 4));
    float s = 0.f;
    #pragma unroll
    for (int u = 0; u < 8; u++)
        s += (f0 + u < 47) ? __expf(val[u] - m) : 0.f;
    s += __shfl_xor(s, 1);
    s += __shfl_xor(s, 2);
    s += __shfl_xor(s, 4);
    float ls = m + __logf(s);
    if (r == 0 && okv) {
        #pragma unroll
        for (int u = 0; u < 8; u++) {
            int f = f0 + u;
            if (f < 47) out[(size_t)v * 47 + f] = val[u] - ls;
        }
    }
}

// ---------------- launch ----------------

extern "C" void kernel_launch(void* const* d_in, const int* in_sizes, int n_in,
                              void* d_out, int out_size, void* d_ws, size_t ws_size,
                              hipStream_t stream) {
    const float* x  = (const float*)d_in[0];
    const int*   ei = (const int*)d_in[1];
    const float* W1 = (const float*)d_in[2];
    const float* b1 = (const float*)d_in[3];
    const float* W2 = (const float*)d_in[4];
    const float* b2 = (const float*)d_in[5];
    float* out = (float*)d_out;

    const int N = in_sizes[0] / 128;
    const int E = in_sizes[1] / 2;
    const int* src = ei;
    const int* dst = ei + E;
    const int NB = ((N - 1) >> NBSHIFT) + 1;   // 98 for N=100000

    char* ws = (char*)d_ws;
    size_t off = 0;
    auto alloc = [&](size_t bytes) {
        void* p = ws + off;
        off += (bytes + 255) & ~(size_t)255;
        return p;
    };
    int*   cnt      = (int*)  alloc((size_t)N * 4);
    int*   gtail    = (int*)  alloc((size_t)128 * 4);
    float* dinv     = (float*)alloc((size_t)N * 4);
    int*   csr_src  = (int*)  alloc((size_t)N * CAP * 4);
    u16*   xw1      = (u16*)  alloc((size_t)N * 64 * 2);
    int2*  bucketed = (int2*) alloc((size_t)NB * BCAP * 8);  // 16.0 MB
    u16*   hbuf     = (u16*)  alloc((size_t)N * 64 * 2);     // bf16 h [N,64]
    u16*   hw2      = (u16*)  alloc((size_t)N * 64 * 2);

    hipMemsetAsync(gtail, 0, 128 * 4, stream);

    const int GB = (N + 63) / 64;
    const int gridA = 512;
    const int seg = (E + gridA - 1) / gridA;
    gemm1_bin<<<GB + gridA, 256, 0, stream>>>(x, W1, xw1, src, dst, gtail, bucketed,
                                              cnt, N, E, NB, seg, GB);
    scatter_csr<<<NB, 512, 0, stream>>>(bucketed, gtail, cnt, csr_src, dinv, N);
    agg1_relu<<<(N + 7) / 8, 256, 0, stream>>>(xw1, csr_src, cnt, dinv, b1, hbuf, N);
    gemm2_tiled<<<(N + 63) / 64, 256, 0, stream>>>(hbuf, W2, hw2, N);
    agg2_lsm<<<(N + 7) / 8, 256, 0, stream>>>(hw2, csr_src, cnt, dinv, b2, out, N);
}